// Round 13
// baseline (274.444 us; speedup 1.0000x reference)
//
#include <hip/hip_runtime.h>
#include <math.h>

#define NN 20000
#define NE 640000
#define NIN 256
#define NH 8
#define HD 16
#define NM 3
#define NF 128   // H*D
#define HID 128
#define NSEG (NM * NN)
#define CAP 128                      // slots per segment (max degree ~59, 12 sigma margin)

typedef __attribute__((ext_vector_type(4))) _Float16 half4;
typedef __attribute__((ext_vector_type(8))) _Float16 half8;
typedef __attribute__((ext_vector_type(4))) float f32x4;
typedef __attribute__((ext_vector_type(4))) int i32x4;
typedef __attribute__((ext_vector_type(4))) float f32x4v;

__device__ __forceinline__ void atomAddF(float* p, float v) {
  unsafeAtomicAdd(p, v);
}

// ---- prep: fp16 conversions + zero cursor/wsum (pure streaming, no atomics) ----
__global__ void k_prep(const float* __restrict__ h, const float* __restrict__ fcW,
                       const float* __restrict__ W1, _Float16* __restrict__ h16,
                       _Float16* __restrict__ WT, _Float16* __restrict__ W1T,
                       int* __restrict__ cursor, float* __restrict__ wsum) {
  int t = blockIdx.x * 256 + threadIdx.x;
  if (t < NN * NIN / 4) {
    float4 v = *(const float4*)(h + 4 * t);
    half4 o = {(_Float16)v.x, (_Float16)v.y, (_Float16)v.z, (_Float16)v.w};
    *(half4*)(h16 + 4 * t) = o;
  }
  if (t < NM * NIN * NF) {              // WT[(m*128+n)*256+k] = fcW[m][k][n]
    int mm = t >> 15;
    int n = (t >> 8) & 127;
    int k = t & 255;
    WT[t] = (_Float16)fcW[(mm << 15) + (k << 7) + n];
  }
  if (t < NF * HID) {                   // W1T[n*128+k] = W1[k][n]
    int n = t >> 7;
    int k = t & 127;
    W1T[t] = (_Float16)W1[k * HID + n];
  }
  if (t < NSEG) cursor[t] = 0;
  if (t < 8) wsum[t] = 0.0f;
}

// ================= fused fill || gemm_elr =================
// 4-byte packed record: (src << 17) | ew_q17;  ew = (q+0.5)/2^17
// single-pass fixed-capacity binning: erec[seg*CAP + pos]; 8 edges/thread
__device__ __forceinline__ void fill_body(int fb, const int* __restrict__ src,
                                          const int* __restrict__ dst,
                                          const float* __restrict__ ew,
                                          int* __restrict__ cursor,
                                          unsigned* __restrict__ erec) {
  int e8 = (fb * 256 + threadIdx.x) * 8;
  if (e8 >= NM * NE) return;          // NM*NE % 8 == 0 -> all-or-none
  i32x4 s0 = __builtin_nontemporal_load((const i32x4*)(src + e8));
  i32x4 s1 = __builtin_nontemporal_load((const i32x4*)(src + e8 + 4));
  i32x4 d0 = __builtin_nontemporal_load((const i32x4*)(dst + e8));
  i32x4 d1 = __builtin_nontemporal_load((const i32x4*)(dst + e8 + 4));
  f32x4v w0 = __builtin_nontemporal_load((const f32x4v*)(ew + e8));
  f32x4v w1 = __builtin_nontemporal_load((const f32x4v*)(ew + e8 + 4));
  const int ss[8] = {s0.x, s0.y, s0.z, s0.w, s1.x, s1.y, s1.z, s1.w};
  const int dd[8] = {d0.x, d0.y, d0.z, d0.w, d1.x, d1.y, d1.z, d1.w};
  const float ww[8] = {w0.x, w0.y, w0.z, w0.w, w1.x, w1.y, w1.z, w1.w};
  int m = e8 / NE;                    // NE % 8 == 0 -> uniform within the octet
  int seg[8], pos[8];
#pragma unroll
  for (int j = 0; j < 8; ++j) {
    seg[j] = m * NN + dd[j];
    pos[j] = atomicAdd(cursor + seg[j], 1);
  }
#pragma unroll
  for (int j = 0; j < 8; ++j) {
    unsigned wq = (unsigned)fminf(ww[j] * 131072.f, 131071.f);
    if (pos[j] < CAP)
      __builtin_nontemporal_store(((unsigned)ss[j] << 17) | wq,
                                  erec + (size_t)seg[j] * CAP + pos[j]);
  }
}

__device__ __forceinline__ void gemm_body(int g, const _Float16* __restrict__ h16,
                                          const _Float16* __restrict__ WT,
                                          const float* __restrict__ al,
                                          const float* __restrict__ ar,
                                          _Float16* __restrict__ fth,
                                          float* __restrict__ el,
                                          float* __restrict__ er) {
  int bx = g % 313, by = g / 313;
  int tid = threadIdx.x;
  int wave = tid >> 6, lane = tid & 63;
  int l15 = lane & 15, kslot = lane >> 4;
  int m = by >> 1;
  int cin = (by & 1) << 6;
  int rowbase = bx * 64 + wave * 16;
  int arow = rowbase + l15;
  bool aok = arow < NN;
  const _Float16* Ap = h16 + (size_t)(aok ? arow : 0) * NIN + kslot * 8;
  const _Float16* Bp = WT + ((size_t)m * NF + cin + l15) * NIN + kslot * 8;
  f32x4 acc[4];
#pragma unroll
  for (int c = 0; c < 4; ++c) acc[c] = (f32x4){0.f, 0.f, 0.f, 0.f};
#pragma unroll
  for (int kk = 0; kk < 8; ++kk) {
    int k0 = kk * 32;
    half8 a = {};
    if (aok) a = *(const half8*)(Ap + k0);
#pragma unroll
    for (int c = 0; c < 4; ++c) {
      half8 b = *(const half8*)(Bp + (size_t)c * 16 * NIN + k0);
      acc[c] = __builtin_amdgcn_mfma_f32_16x16x32_f16(a, b, acc[c], 0, 0, 0);
    }
  }
  int orow0 = rowbase + kslot * 4;
#pragma unroll
  for (int j = 0; j < 4; ++j) {
    int r = orow0 + j;
    if (r < NN) {
      _Float16* op = fth + ((size_t)m * NN + r) * NF + cin + l15;
#pragma unroll
      for (int c = 0; c < 4; ++c) op[c * 16] = (_Float16)acc[c][j];
    }
  }
  float alr[4], arr_[4];
#pragma unroll
  for (int c = 0; c < 4; ++c) {
    int head = (cin >> 4) + c;
    alr[c] = al[(m * NH + head) * HD + l15];
    arr_[c] = ar[(m * NH + head) * HD + l15];
  }
#pragma unroll
  for (int c = 0; c < 4; ++c) {
    int head = (cin >> 4) + c;
#pragma unroll
    for (int j = 0; j < 4; ++j) {
      float v = acc[c][j] * alr[c];
      float u = acc[c][j] * arr_[c];
#pragma unroll
      for (int off = 1; off < 16; off <<= 1) {
        v += __shfl_xor(v, off);
        u += __shfl_xor(u, off);
      }
      int r = orow0 + j;
      if (l15 == 0 && r < NN) {
        size_t idx = ((size_t)m * NN + r) * NH + head;
        el[idx] = v;
        er[idx] = u;
      }
    }
  }
}

// grid 2816: idx<2814 -> idx%3==0 fill (938), else gemm; idx 2814/2815 -> gemm tail
__global__ __launch_bounds__(256) void k_fill_gemm(
    const int* __restrict__ src, const int* __restrict__ dst,
    const float* __restrict__ ew, int* __restrict__ cursor,
    unsigned* __restrict__ erec, const _Float16* __restrict__ h16,
    const _Float16* __restrict__ WT, const float* __restrict__ al,
    const float* __restrict__ ar, _Float16* __restrict__ fth,
    float* __restrict__ el, float* __restrict__ er) {
  int idx = blockIdx.x;
  if (idx < 2814) {
    int r = idx % 3;
    int b = idx / 3;
    if (r == 0) fill_body(b, src, dst, ew, cursor, erec);
    else gemm_body(b * 2 + (r - 1), h16, WT, al, ar, fth, el, er);
  } else {
    gemm_body(1876 + (idx - 2814), h16, WT, al, ar, fth, el, er);
  }
}

// ---- fused per-dst ONLINE softmax + aggregation, grid-level column split ----
// 2*NSEG waves: wid < NSEG -> cols [0,64); else cols [64,128).
// per wave: 8 edges/iter (8 lanes/edge, 8 cols/lane)
__global__ __launch_bounds__(256) void k_aggr2p(
    const int* __restrict__ cursor, const unsigned* __restrict__ erec,
    const float* __restrict__ el, const float* __restrict__ er,
    const _Float16* __restrict__ fth, const float* __restrict__ bias,
    _Float16* __restrict__ zh) {
  int wid = (blockIdx.x * 256 + threadIdx.x) >> 6;
  int lane = threadIdx.x & 63;
  if (wid >= 2 * NSEG) return;
  int pass = wid >= NSEG ? 1 : 0;
  int seg = wid - pass * NSEG;
  int m = seg / NN;
  int cnt = cursor[seg];
  cnt = cnt < CAP ? cnt : CAP;
  const unsigned* rp = erec + (size_t)seg * CAP;
  int g = lane >> 3, l8 = lane & 7;
  int c0 = pass * 64 + l8 * 8;        // 8 fp16 cols per lane
  int h2 = c0 >> 4;                   // head of my cols
  float er2 = er[seg * NH + h2];
  const float* elm = el + (size_t)m * NN * NH;
  const _Float16* fhm = fth + (size_t)m * NN * NF;

  float mx = -1e30f, sm = 0.f;
  float acc[8] = {};
  for (int i = g; i < cnt; i += 8) {
    unsigned rec = rp[i];
    int s = rec >> 17;
    float w = ((rec & 131071u) + 0.5f) * (1.f / 131072.f);
    float x = (elm[s * NH + h2] + er2) * w;
    x = x > 0.f ? x : 0.2f * x;
    float nmx = fmaxf(mx, x);
    float f = __expf(mx - nmx);
    float e = __expf(x - nmx);
    mx = nmx;
    sm = sm * f + e;
    half8 q = *(const half8*)(fhm + (size_t)s * NF + c0);
#pragma unroll
    for (int k = 0; k < 8; ++k) acc[k] = fmaf(e, (float)q[k], acc[k] * f);
  }
#pragma unroll
  for (int d = 8; d <= 32; d <<= 1) {
    float omx = __shfl_xor(mx, d);
    float osm = __shfl_xor(sm, d);
    float nmx = fmaxf(mx, omx);
    float f1 = __expf(mx - nmx), f2 = __expf(omx - nmx);
    sm = sm * f1 + osm * f2;
#pragma unroll
    for (int k = 0; k < 8; ++k) {
      float o = __shfl_xor(acc[k], d);
      acc[k] = acc[k] * f1 + o * f2;
    }
    mx = nmx;
  }
  if (g == 0) {
    float inv = sm > 0.f ? 1.f / sm : 0.f;
    const float* bp = bias + m * NF + c0;
    half8 zo;
#pragma unroll
    for (int k = 0; k < 8; ++k) {
      float q = fmaf(acc[k], inv, bp[k]);
      q = q > 0.f ? q : __expf(q) - 1.f;
      zo[k] = (_Float16)q;
    }
    *(half8*)(zh + (size_t)seg * NF + c0) = zo;
  }
}

// ---- semantic: wsum[m] = sum_n w2 . tanh(zh[n,m,:] @ W1 + b1), MFMA ----
__global__ __launch_bounds__(256) void k_semgemm_mfma(
    const _Float16* __restrict__ zh, const _Float16* __restrict__ W1T,
    const float* __restrict__ b1, const float* __restrict__ w2,
    float* __restrict__ wsum) {
  __shared__ float msum[NM];
  int tid = threadIdx.x;
  if (tid < NM) msum[tid] = 0.f;
  __syncthreads();
  int wave = tid >> 6, lane = tid & 63;
  int l15 = lane & 15, kslot = lane >> 4;
  int rowbase = blockIdx.x * 64 + wave * 16;
  int arow = rowbase + l15;
  bool aok = arow < NSEG;
  const _Float16* Ap = zh + (size_t)(aok ? arow : 0) * NF + kslot * 8;
  const _Float16* Bp = W1T + (size_t)l15 * HID + kslot * 8;
  f32x4 acc[8];
#pragma unroll
  for (int c = 0; c < 8; ++c) acc[c] = (f32x4){0.f, 0.f, 0.f, 0.f};
#pragma unroll
  for (int kk = 0; kk < 4; ++kk) {
    int k0 = kk * 32;
    half8 a = {};
    if (aok) a = *(const half8*)(Ap + k0);
#pragma unroll
    for (int c = 0; c < 8; ++c) {
      half8 b = *(const half8*)(Bp + (size_t)c * 16 * HID + k0);
      acc[c] = __builtin_amdgcn_mfma_f32_16x16x32_f16(a, b, acc[c], 0, 0, 0);
    }
  }
  float p[4] = {0.f, 0.f, 0.f, 0.f};
#pragma unroll
  for (int c = 0; c < 8; ++c) {
    int col = c * 16 + l15;
    float b1r = b1[col];
    float w2r = w2[col];
#pragma unroll
    for (int j = 0; j < 4; ++j) p[j] += w2r * tanhf(acc[c][j] + b1r);
  }
#pragma unroll
  for (int j = 0; j < 4; ++j) {
#pragma unroll
    for (int off = 1; off < 16; off <<= 1) p[j] += __shfl_xor(p[j], off);
  }
  if (l15 == 0) {
#pragma unroll
    for (int j = 0; j < 4; ++j) {
      int r = rowbase + kslot * 4 + j;
      if (r < NSEG) atomicAdd(&msum[r / NN], p[j]);
    }
  }
  __syncthreads();
  if (tid < NM) {
    float v = msum[tid];
    if (v != 0.f) atomAddF(wsum + tid, v);
  }
}

// ---- output combine (vectorized, beta inline) ----
__global__ void k_out8(const _Float16* __restrict__ zh, const float* __restrict__ wsum,
                       float* __restrict__ out) {
  int t = blockIdx.x * 256 + threadIdx.x;
  if (t >= NN * NF / 8) return;
  float w0 = wsum[0] * (1.f / NN);
  float w1 = wsum[1] * (1.f / NN);
  float w2v = wsum[2] * (1.f / NN);
  float mxw = fmaxf(w0, fmaxf(w1, w2v));
  float e0 = __expf(w0 - mxw), e1 = __expf(w1 - mxw), e2 = __expf(w2v - mxw);
  float inv = 1.f / (e0 + e1 + e2);
  e0 *= inv; e1 *= inv; e2 *= inv;
  size_t base = (size_t)t * 8;
  half8 z0 = *(const half8*)(zh + base);
  half8 z1 = *(const half8*)(zh + (size_t)NN * NF + base);
  half8 z2 = *(const half8*)(zh + (size_t)2 * NN * NF + base);
  float o[8];
#pragma unroll
  for (int k = 0; k < 8; ++k)
    o[k] = e0 * (float)z0[k] + e1 * (float)z1[k] + e2 * (float)z2[k];
  *(float4*)(out + base) = make_float4(o[0], o[1], o[2], o[3]);
  *(float4*)(out + base + 4) = make_float4(o[4], o[5], o[6], o[7]);
}

extern "C" void kernel_launch(void* const* d_in, const int* in_sizes, int n_in,
                              void* d_out, int out_size, void* d_ws, size_t ws_size,
                              hipStream_t stream) {
  (void)in_sizes; (void)n_in; (void)out_size; (void)ws_size;
  const float* h    = (const float*)d_in[0];
  const float* fcW  = (const float*)d_in[1];
  const float* al   = (const float*)d_in[2];
  const float* ar   = (const float*)d_in[3];
  const float* bias = (const float*)d_in[4];
  const float* ew   = (const float*)d_in[5];
  const float* W1   = (const float*)d_in[6];
  const float* b1   = (const float*)d_in[7];
  const float* w2   = (const float*)d_in[8];
  const int* src    = (const int*)d_in[9];
  const int* dst    = (const int*)d_in[10];
  float* out = (float*)d_out;

  char* base = (char*)d_ws;
  size_t o = 0;
  int* cursor = (int*)(base + o); o += (size_t)NSEG * 4;
  float* wsum = (float*)(base + o); o += 8 * 4;
  o = (o + 15) & ~(size_t)15;
  unsigned* erec = (unsigned*)(base + o); o += (size_t)NSEG * CAP * 4;  // 30.7 MB
  float* el   = (float*)(base + o); o += (size_t)NSEG * NH * 4;
  float* er   = (float*)(base + o); o += (size_t)NSEG * NH * 4;
  _Float16* fth = (_Float16*)(base + o); o += (size_t)NM * NN * NF * 2;
  _Float16* h16 = (_Float16*)(base + o); o += (size_t)NN * NIN * 2;
  _Float16* WT  = (_Float16*)(base + o); o += (size_t)NM * NIN * NF * 2;
  _Float16* W1T = (_Float16*)(base + o); o += (size_t)NF * HID * 2;
  _Float16* zh  = (_Float16*)(base + o); o += (size_t)NM * NN * NF * 2;
  // total ~76 MB

  hipLaunchKernelGGL(k_prep, dim3(5000), dim3(256), 0, stream,
                     h, fcW, W1, h16, WT, W1T, cursor, wsum);
  hipLaunchKernelGGL(k_fill_gemm, dim3(2816), dim3(256), 0, stream,
                     src, dst, ew, cursor, erec, h16, WT, al, ar, fth, el, er);
  hipLaunchKernelGGL(k_aggr2p, dim3(30000), dim3(256), 0, stream,
                     cursor, erec, el, er, fth, bias, zh);
  hipLaunchKernelGGL(k_semgemm_mfma, dim3(938), dim3(256), 0, stream,
                     zh, W1T, b1, w2, wsum);
  hipLaunchKernelGGL(k_out8, dim3(1250), dim3(256), 0, stream, zh, wsum, out);
}

// Round 14
// 274.189 us; speedup vs baseline: 1.0009x; 1.0009x over previous
//
#include <hip/hip_runtime.h>
#include <math.h>

#define NN 20000
#define NE 640000
#define NIN 256
#define NH 8
#define HD 16
#define NM 3
#define NF 128   // H*D
#define HID 128
#define NSEG (NM * NN)
#define CAP 128                      // slots per segment (max degree ~59, 12 sigma margin)

typedef __attribute__((ext_vector_type(4))) _Float16 half4;
typedef __attribute__((ext_vector_type(8))) _Float16 half8;
typedef __attribute__((ext_vector_type(4))) float f32x4;

__device__ __forceinline__ void atomAddF(float* p, float v) {
  unsafeAtomicAdd(p, v);
}

// ---- prep: fp16 conversions + zero cursor/wsum (pure streaming, no atomics) ----
__global__ void k_prep(const float* __restrict__ h, const float* __restrict__ fcW,
                       const float* __restrict__ W1, _Float16* __restrict__ h16,
                       _Float16* __restrict__ WT, _Float16* __restrict__ W1T,
                       int* __restrict__ cursor, float* __restrict__ wsum) {
  int t = blockIdx.x * 256 + threadIdx.x;
  if (t < NN * NIN / 4) {
    float4 v = *(const float4*)(h + 4 * t);
    half4 o = {(_Float16)v.x, (_Float16)v.y, (_Float16)v.z, (_Float16)v.w};
    *(half4*)(h16 + 4 * t) = o;
  }
  if (t < NM * NIN * NF) {              // WT[(m*128+n)*256+k] = fcW[m][k][n]
    int mm = t >> 15;
    int n = (t >> 8) & 127;
    int k = t & 255;
    WT[t] = (_Float16)fcW[(mm << 15) + (k << 7) + n];
  }
  if (t < NF * HID) {                   // W1T[n*128+k] = W1[k][n]
    int n = t >> 7;
    int k = t & 127;
    W1T[t] = (_Float16)W1[k * HID + n];
  }
  if (t < NSEG) cursor[t] = 0;
  if (t < 8) wsum[t] = 0.0f;
}

// ================= fused fill || gemm_elr =================
// 4-byte packed record: (src << 17) | ew_q17;  ew = (q+0.5)/2^17
// single-pass fixed-capacity binning: erec[seg*CAP + pos]; 4 edges/thread
__device__ __forceinline__ void fill_body(int fb, const int* __restrict__ src,
                                          const int* __restrict__ dst,
                                          const float* __restrict__ ew,
                                          int* __restrict__ cursor,
                                          unsigned* __restrict__ erec) {
  int e4 = (fb * 256 + threadIdx.x) * 4;
  if (e4 >= NM * NE) return;
  int4 d4 = *(const int4*)(dst + e4);
  int4 s4 = *(const int4*)(src + e4);
  float4 w4 = *(const float4*)(ew + e4);
  const int dd[4] = {d4.x, d4.y, d4.z, d4.w};
  const int ss[4] = {s4.x, s4.y, s4.z, s4.w};
  const float ww[4] = {w4.x, w4.y, w4.z, w4.w};
  int seg[4], pos[4];
#pragma unroll
  for (int j = 0; j < 4; ++j) {
    int m = (e4 + j) / NE;
    seg[j] = m * NN + dd[j];
    pos[j] = atomicAdd(cursor + seg[j], 1);
  }
#pragma unroll
  for (int j = 0; j < 4; ++j) {
    unsigned wq = (unsigned)fminf(ww[j] * 131072.f, 131071.f);
    if (pos[j] < CAP)
      __builtin_nontemporal_store(((unsigned)ss[j] << 17) | wq,
                                  erec + (size_t)seg[j] * CAP + pos[j]);
  }
}

__device__ __forceinline__ void gemm_body(int g, const _Float16* __restrict__ h16,
                                          const _Float16* __restrict__ WT,
                                          const float* __restrict__ al,
                                          const float* __restrict__ ar,
                                          _Float16* __restrict__ fth,
                                          float* __restrict__ el,
                                          float* __restrict__ er) {
  int bx = g % 313, by = g / 313;
  int tid = threadIdx.x;
  int wave = tid >> 6, lane = tid & 63;
  int l15 = lane & 15, kslot = lane >> 4;
  int m = by >> 1;
  int cin = (by & 1) << 6;
  int rowbase = bx * 64 + wave * 16;
  int arow = rowbase + l15;
  bool aok = arow < NN;
  const _Float16* Ap = h16 + (size_t)(aok ? arow : 0) * NIN + kslot * 8;
  const _Float16* Bp = WT + ((size_t)m * NF + cin + l15) * NIN + kslot * 8;
  f32x4 acc[4];
#pragma unroll
  for (int c = 0; c < 4; ++c) acc[c] = (f32x4){0.f, 0.f, 0.f, 0.f};
#pragma unroll
  for (int kk = 0; kk < 8; ++kk) {
    int k0 = kk * 32;
    half8 a = {};
    if (aok) a = *(const half8*)(Ap + k0);
#pragma unroll
    for (int c = 0; c < 4; ++c) {
      half8 b = *(const half8*)(Bp + (size_t)c * 16 * NIN + k0);
      acc[c] = __builtin_amdgcn_mfma_f32_16x16x32_f16(a, b, acc[c], 0, 0, 0);
    }
  }
  int orow0 = rowbase + kslot * 4;
#pragma unroll
  for (int j = 0; j < 4; ++j) {
    int r = orow0 + j;
    if (r < NN) {
      _Float16* op = fth + ((size_t)m * NN + r) * NF + cin + l15;
#pragma unroll
      for (int c = 0; c < 4; ++c) op[c * 16] = (_Float16)acc[c][j];
    }
  }
  float alr[4], arr_[4];
#pragma unroll
  for (int c = 0; c < 4; ++c) {
    int head = (cin >> 4) + c;
    alr[c] = al[(m * NH + head) * HD + l15];
    arr_[c] = ar[(m * NH + head) * HD + l15];
  }
#pragma unroll
  for (int c = 0; c < 4; ++c) {
    int head = (cin >> 4) + c;
#pragma unroll
    for (int j = 0; j < 4; ++j) {
      float v = acc[c][j] * alr[c];
      float u = acc[c][j] * arr_[c];
#pragma unroll
      for (int off = 1; off < 16; off <<= 1) {
        v += __shfl_xor(v, off);
        u += __shfl_xor(u, off);
      }
      int r = orow0 + j;
      if (l15 == 0 && r < NN) {
        size_t idx = ((size_t)m * NN + r) * NH + head;
        el[idx] = v;
        er[idx] = u;
      }
    }
  }
}

// grid 3754: idx<2814 -> pattern {fill,fill,gemm}; idx>=2814 -> gemm tail
// fills: 938 triplets x 2 = 1876 slots (guard fb<1875); gemms: 938 + 940 = 1878
__global__ __launch_bounds__(256) void k_fill_gemm(
    const int* __restrict__ src, const int* __restrict__ dst,
    const float* __restrict__ ew, int* __restrict__ cursor,
    unsigned* __restrict__ erec, const _Float16* __restrict__ h16,
    const _Float16* __restrict__ WT, const float* __restrict__ al,
    const float* __restrict__ ar, _Float16* __restrict__ fth,
    float* __restrict__ el, float* __restrict__ er) {
  int idx = blockIdx.x;
  if (idx < 2814) {
    int r = idx % 3;
    int b = idx / 3;
    if (r < 2) {
      int fb = b * 2 + r;
      if (fb < 1875) fill_body(fb, src, dst, ew, cursor, erec);
    } else {
      gemm_body(b, h16, WT, al, ar, fth, el, er);
    }
  } else {
    gemm_body(938 + (idx - 2814), h16, WT, al, ar, fth, el, er);
  }
}

// ---- fused per-dst ONLINE softmax + aggregation ----
// one wave per (m, dst); 8 edges/iter (8 lanes/edge, 16 cols/lane)
__global__ __launch_bounds__(256) void k_aggr8(
    const int* __restrict__ cursor, const unsigned* __restrict__ erec,
    const float* __restrict__ el, const float* __restrict__ er,
    const _Float16* __restrict__ fth, const float* __restrict__ bias,
    _Float16* __restrict__ zh) {
  int wid = (blockIdx.x * 256 + threadIdx.x) >> 6;
  int lane = threadIdx.x & 63;
  if (wid >= NSEG) return;
  int m = wid / NN;
  int cnt = cursor[wid];
  cnt = cnt < CAP ? cnt : CAP;
  const unsigned* rp = erec + (size_t)wid * CAP;
  int g = lane >> 3, l8 = lane & 7;
  int h2 = l8;
  int c0 = l8 * 16;
  float er2 = er[wid * NH + h2];
  const float* elm = el + (size_t)m * NN * NH;
  const _Float16* fhm = fth + (size_t)m * NN * NF;

  float mx = -1e30f, sm = 0.f;
  float acc[16] = {};
  for (int i = g; i < cnt; i += 8) {
    unsigned rec = rp[i];
    int s = rec >> 17;
    float w = ((rec & 131071u) + 0.5f) * (1.f / 131072.f);
    float x = (elm[s * NH + h2] + er2) * w;
    x = x > 0.f ? x : 0.2f * x;
    float nmx = fmaxf(mx, x);
    float f = __expf(mx - nmx);
    float e = __expf(x - nmx);
    mx = nmx;
    sm = sm * f + e;
    const _Float16* fp = fhm + (size_t)s * NF + c0;
    half8 q0 = *(const half8*)(fp);
    half8 q1 = *(const half8*)(fp + 8);
#pragma unroll
    for (int k = 0; k < 8; ++k) acc[k] = fmaf(e, (float)q0[k], acc[k] * f);
#pragma unroll
    for (int k = 0; k < 8; ++k) acc[8 + k] = fmaf(e, (float)q1[k], acc[8 + k] * f);
  }
#pragma unroll
  for (int d = 8; d <= 32; d <<= 1) {
    float omx = __shfl_xor(mx, d);
    float osm = __shfl_xor(sm, d);
    float nmx = fmaxf(mx, omx);
    float f1 = __expf(mx - nmx), f2 = __expf(omx - nmx);
    sm = sm * f1 + osm * f2;
#pragma unroll
    for (int k = 0; k < 16; ++k) {
      float o = __shfl_xor(acc[k], d);
      acc[k] = acc[k] * f1 + o * f2;
    }
    mx = nmx;
  }
  if (g == 0) {
    float inv = sm > 0.f ? 1.f / sm : 0.f;
    const float* bp = bias + m * NF + c0;
    half8 zo0, zo1;
#pragma unroll
    for (int k = 0; k < 8; ++k) {
      float q = fmaf(acc[k], inv, bp[k]);
      q = q > 0.f ? q : __expf(q) - 1.f;
      zo0[k] = (_Float16)q;
      float q2 = fmaf(acc[8 + k], inv, bp[8 + k]);
      q2 = q2 > 0.f ? q2 : __expf(q2) - 1.f;
      zo1[k] = (_Float16)q2;
    }
    *(half8*)(zh + (size_t)wid * NF + c0) = zo0;
    *(half8*)(zh + (size_t)wid * NF + c0 + 8) = zo1;
  }
}

// ---- semantic: wsum[m] = sum_n w2 . tanh(zh[n,m,:] @ W1 + b1), MFMA ----
__global__ __launch_bounds__(256) void k_semgemm_mfma(
    const _Float16* __restrict__ zh, const _Float16* __restrict__ W1T,
    const float* __restrict__ b1, const float* __restrict__ w2,
    float* __restrict__ wsum) {
  __shared__ float msum[NM];
  int tid = threadIdx.x;
  if (tid < NM) msum[tid] = 0.f;
  __syncthreads();
  int wave = tid >> 6, lane = tid & 63;
  int l15 = lane & 15, kslot = lane >> 4;
  int rowbase = blockIdx.x * 64 + wave * 16;
  int arow = rowbase + l15;
  bool aok = arow < NSEG;
  const _Float16* Ap = zh + (size_t)(aok ? arow : 0) * NF + kslot * 8;
  const _Float16* Bp = W1T + (size_t)l15 * HID + kslot * 8;
  f32x4 acc[8];
#pragma unroll
  for (int c = 0; c < 8; ++c) acc[c] = (f32x4){0.f, 0.f, 0.f, 0.f};
#pragma unroll
  for (int kk = 0; kk < 4; ++kk) {
    int k0 = kk * 32;
    half8 a = {};
    if (aok) a = *(const half8*)(Ap + k0);
#pragma unroll
    for (int c = 0; c < 8; ++c) {
      half8 b = *(const half8*)(Bp + (size_t)c * 16 * HID + k0);
      acc[c] = __builtin_amdgcn_mfma_f32_16x16x32_f16(a, b, acc[c], 0, 0, 0);
    }
  }
  float p[4] = {0.f, 0.f, 0.f, 0.f};
#pragma unroll
  for (int c = 0; c < 8; ++c) {
    int col = c * 16 + l15;
    float b1r = b1[col];
    float w2r = w2[col];
#pragma unroll
    for (int j = 0; j < 4; ++j) p[j] += w2r * tanhf(acc[c][j] + b1r);
  }
#pragma unroll
  for (int j = 0; j < 4; ++j) {
#pragma unroll
    for (int off = 1; off < 16; off <<= 1) p[j] += __shfl_xor(p[j], off);
  }
  if (l15 == 0) {
#pragma unroll
    for (int j = 0; j < 4; ++j) {
      int r = rowbase + kslot * 4 + j;
      if (r < NSEG) atomicAdd(&msum[r / NN], p[j]);
    }
  }
  __syncthreads();
  if (tid < NM) {
    float v = msum[tid];
    if (v != 0.f) atomAddF(wsum + tid, v);
  }
}

// ---- output combine (vectorized, beta inline) ----
__global__ void k_out8(const _Float16* __restrict__ zh, const float* __restrict__ wsum,
                       float* __restrict__ out) {
  int t = blockIdx.x * 256 + threadIdx.x;
  if (t >= NN * NF / 8) return;
  float w0 = wsum[0] * (1.f / NN);
  float w1 = wsum[1] * (1.f / NN);
  float w2v = wsum[2] * (1.f / NN);
  float mxw = fmaxf(w0, fmaxf(w1, w2v));
  float e0 = __expf(w0 - mxw), e1 = __expf(w1 - mxw), e2 = __expf(w2v - mxw);
  float inv = 1.f / (e0 + e1 + e2);
  e0 *= inv; e1 *= inv; e2 *= inv;
  size_t base = (size_t)t * 8;
  half8 z0 = *(const half8*)(zh + base);
  half8 z1 = *(const half8*)(zh + (size_t)NN * NF + base);
  half8 z2 = *(const half8*)(zh + (size_t)2 * NN * NF + base);
  float o[8];
#pragma unroll
  for (int k = 0; k < 8; ++k)
    o[k] = e0 * (float)z0[k] + e1 * (float)z1[k] + e2 * (float)z2[k];
  *(float4*)(out + base) = make_float4(o[0], o[1], o[2], o[3]);
  *(float4*)(out + base + 4) = make_float4(o[4], o[5], o[6], o[7]);
}

extern "C" void kernel_launch(void* const* d_in, const int* in_sizes, int n_in,
                              void* d_out, int out_size, void* d_ws, size_t ws_size,
                              hipStream_t stream) {
  (void)in_sizes; (void)n_in; (void)out_size; (void)ws_size;
  const float* h    = (const float*)d_in[0];
  const float* fcW  = (const float*)d_in[1];
  const float* al   = (const float*)d_in[2];
  const float* ar   = (const float*)d_in[3];
  const float* bias = (const float*)d_in[4];
  const float* ew   = (const float*)d_in[5];
  const float* W1   = (const float*)d_in[6];
  const float* b1   = (const float*)d_in[7];
  const float* w2   = (const float*)d_in[8];
  const int* src    = (const int*)d_in[9];
  const int* dst    = (const int*)d_in[10];
  float* out = (float*)d_out;

  char* base = (char*)d_ws;
  size_t o = 0;
  int* cursor = (int*)(base + o); o += (size_t)NSEG * 4;
  float* wsum = (float*)(base + o); o += 8 * 4;
  o = (o + 15) & ~(size_t)15;
  unsigned* erec = (unsigned*)(base + o); o += (size_t)NSEG * CAP * 4;  // 30.7 MB
  float* el   = (float*)(base + o); o += (size_t)NSEG * NH * 4;
  float* er   = (float*)(base + o); o += (size_t)NSEG * NH * 4;
  _Float16* fth = (_Float16*)(base + o); o += (size_t)NM * NN * NF * 2;
  _Float16* h16 = (_Float16*)(base + o); o += (size_t)NN * NIN * 2;
  _Float16* WT  = (_Float16*)(base + o); o += (size_t)NM * NIN * NF * 2;
  _Float16* W1T = (_Float16*)(base + o); o += (size_t)NF * HID * 2;
  _Float16* zh  = (_Float16*)(base + o); o += (size_t)NM * NN * NF * 2;
  // total ~76 MB

  hipLaunchKernelGGL(k_prep, dim3(5000), dim3(256), 0, stream,
                     h, fcW, W1, h16, WT, W1T, cursor, wsum);
  hipLaunchKernelGGL(k_fill_gemm, dim3(3754), dim3(256), 0, stream,
                     src, dst, ew, cursor, erec, h16, WT, al, ar, fth, el, er);
  hipLaunchKernelGGL(k_aggr8, dim3(15000), dim3(256), 0, stream,
                     cursor, erec, el, er, fth, bias, zh);
  hipLaunchKernelGGL(k_semgemm_mfma, dim3(938), dim3(256), 0, stream,
                     zh, W1T, b1, w2, wsum);
  hipLaunchKernelGGL(k_out8, dim3(1250), dim3(256), 0, stream, zh, wsum, out);
}

// Round 15
// 230.589 us; speedup vs baseline: 1.1902x; 1.1891x over previous
//
#include <hip/hip_runtime.h>
#include <math.h>

#define NN 20000
#define NE 640000
#define NIN 256
#define NH 8
#define HD 16
#define NM 3
#define NF 128   // H*D
#define HID 128
#define NSEG (NM * NN)
#define CAP 128                      // slots per segment (max degree ~59, 12 sigma margin)

typedef __attribute__((ext_vector_type(4))) _Float16 half4;
typedef __attribute__((ext_vector_type(8))) _Float16 half8;
typedef __attribute__((ext_vector_type(4))) float f32x4;

__device__ __forceinline__ void atomAddF(float* p, float v) {
  unsafeAtomicAdd(p, v);
}

// ---- prep: fp16 conversions + zero cursor/wsum (pure streaming, no atomics) ----
__global__ void k_prep(const float* __restrict__ h, const float* __restrict__ fcW,
                       const float* __restrict__ W1, _Float16* __restrict__ h16,
                       _Float16* __restrict__ WT, _Float16* __restrict__ W1T,
                       int* __restrict__ cursor, float* __restrict__ wsum) {
  int t = blockIdx.x * 256 + threadIdx.x;
  if (t < NN * NIN / 4) {
    float4 v = *(const float4*)(h + 4 * t);
    half4 o = {(_Float16)v.x, (_Float16)v.y, (_Float16)v.z, (_Float16)v.w};
    *(half4*)(h16 + 4 * t) = o;
  }
  if (t < NM * NIN * NF) {              // WT[(m*128+n)*256+k] = fcW[m][k][n]
    int mm = t >> 15;
    int n = (t >> 8) & 127;
    int k = t & 255;
    WT[t] = (_Float16)fcW[(mm << 15) + (k << 7) + n];
  }
  if (t < NF * HID) {                   // W1T[n*128+k] = W1[k][n]
    int n = t >> 7;
    int k = t & 127;
    W1T[t] = (_Float16)W1[k * HID + n];
  }
  if (t < NSEG) cursor[t] = 0;
  if (t < 8) wsum[t] = 0.0f;
}

// ================= fused fill || gemm_elr =================
// 4-byte packed record: (src << 17) | ew_q17;  ew = (q+0.5)/2^17
// single-pass fixed-capacity binning: erec[seg*CAP + pos]; 4 edges/thread
__device__ __forceinline__ void fill_body(int fb, const int* __restrict__ src,
                                          const int* __restrict__ dst,
                                          const float* __restrict__ ew,
                                          int* __restrict__ cursor,
                                          unsigned* __restrict__ erec) {
  int e4 = (fb * 256 + threadIdx.x) * 4;
  if (e4 >= NM * NE) return;
  int4 d4 = *(const int4*)(dst + e4);
  int4 s4 = *(const int4*)(src + e4);
  float4 w4 = *(const float4*)(ew + e4);
  const int dd[4] = {d4.x, d4.y, d4.z, d4.w};
  const int ss[4] = {s4.x, s4.y, s4.z, s4.w};
  const float ww[4] = {w4.x, w4.y, w4.z, w4.w};
  int seg[4], pos[4];
#pragma unroll
  for (int j = 0; j < 4; ++j) {
    int m = (e4 + j) / NE;
    seg[j] = m * NN + dd[j];
    pos[j] = atomicAdd(cursor + seg[j], 1);
  }
#pragma unroll
  for (int j = 0; j < 4; ++j) {
    unsigned wq = (unsigned)fminf(ww[j] * 131072.f, 131071.f);
    if (pos[j] < CAP)
      __builtin_nontemporal_store(((unsigned)ss[j] << 17) | wq,
                                  erec + (size_t)seg[j] * CAP + pos[j]);
  }
}

__device__ __forceinline__ void gemm_body(int g, const _Float16* __restrict__ h16,
                                          const _Float16* __restrict__ WT,
                                          const float* __restrict__ al,
                                          const float* __restrict__ ar,
                                          _Float16* __restrict__ fth,
                                          float* __restrict__ el,
                                          float* __restrict__ er) {
  int bx = g % 313, by = g / 313;
  int tid = threadIdx.x;
  int wave = tid >> 6, lane = tid & 63;
  int l15 = lane & 15, kslot = lane >> 4;
  int m = by >> 1;
  int cin = (by & 1) << 6;
  int rowbase = bx * 64 + wave * 16;
  int arow = rowbase + l15;
  bool aok = arow < NN;
  const _Float16* Ap = h16 + (size_t)(aok ? arow : 0) * NIN + kslot * 8;
  const _Float16* Bp = WT + ((size_t)m * NF + cin + l15) * NIN + kslot * 8;
  f32x4 acc[4];
#pragma unroll
  for (int c = 0; c < 4; ++c) acc[c] = (f32x4){0.f, 0.f, 0.f, 0.f};
#pragma unroll
  for (int kk = 0; kk < 8; ++kk) {
    int k0 = kk * 32;
    half8 a = {};
    if (aok) a = *(const half8*)(Ap + k0);
#pragma unroll
    for (int c = 0; c < 4; ++c) {
      half8 b = *(const half8*)(Bp + (size_t)c * 16 * NIN + k0);
      acc[c] = __builtin_amdgcn_mfma_f32_16x16x32_f16(a, b, acc[c], 0, 0, 0);
    }
  }
  int orow0 = rowbase + kslot * 4;
#pragma unroll
  for (int j = 0; j < 4; ++j) {
    int r = orow0 + j;
    if (r < NN) {
      _Float16* op = fth + ((size_t)m * NN + r) * NF + cin + l15;
#pragma unroll
      for (int c = 0; c < 4; ++c) op[c * 16] = (_Float16)acc[c][j];
    }
  }
  float alr[4], arr_[4];
#pragma unroll
  for (int c = 0; c < 4; ++c) {
    int head = (cin >> 4) + c;
    alr[c] = al[(m * NH + head) * HD + l15];
    arr_[c] = ar[(m * NH + head) * HD + l15];
  }
#pragma unroll
  for (int c = 0; c < 4; ++c) {
    int head = (cin >> 4) + c;
#pragma unroll
    for (int j = 0; j < 4; ++j) {
      float v = acc[c][j] * alr[c];
      float u = acc[c][j] * arr_[c];
#pragma unroll
      for (int off = 1; off < 16; off <<= 1) {
        v += __shfl_xor(v, off);
        u += __shfl_xor(u, off);
      }
      int r = orow0 + j;
      if (l15 == 0 && r < NN) {
        size_t idx = ((size_t)m * NN + r) * NH + head;
        el[idx] = v;
        er[idx] = u;
      }
    }
  }
}

// grid 3756: even idx -> fill (1875 active), odd idx -> gemm (1878 active)  [round-11 optimum]
__global__ __launch_bounds__(256) void k_fill_gemm(
    const int* __restrict__ src, const int* __restrict__ dst,
    const float* __restrict__ ew, int* __restrict__ cursor,
    unsigned* __restrict__ erec, const _Float16* __restrict__ h16,
    const _Float16* __restrict__ WT, const float* __restrict__ al,
    const float* __restrict__ ar, _Float16* __restrict__ fth,
    float* __restrict__ el, float* __restrict__ er) {
  int idx = blockIdx.x;
  int half_ = idx >> 1;
  if (idx & 1) {
    if (half_ < 1878) gemm_body(half_, h16, WT, al, ar, fth, el, er);
  } else {
    if (half_ < 1875) fill_body(half_, src, dst, ew, cursor, erec);
  }
}

// ---- fused per-dst ONLINE softmax + aggregation, XCD-affine metapath mapping ----
// wg i -> XCD i%8 (dispatch heuristic). XCDs {0,1,2}->m0, {3,4,5}->m1, {6,7}->m2.
// Each block: rank j within its XCD group -> segments [j*4, j*4+4) of metapath g.
// per wave: 8 edges/iter (8 lanes/edge, 16 cols/lane)
__global__ __launch_bounds__(256) void k_aggr8(
    const int* __restrict__ cursor, const unsigned* __restrict__ erec,
    const float* __restrict__ el, const float* __restrict__ er,
    const _Float16* __restrict__ fth, const float* __restrict__ bias,
    _Float16* __restrict__ zh) {
  int b = blockIdx.x;
  int x = b & 7;                      // presumed XCD id
  int grp, gi, gsz;
  if (x < 3)      { grp = 0; gi = x;     gsz = 3; }
  else if (x < 6) { grp = 1; gi = x - 3; gsz = 3; }
  else            { grp = 2; gi = x - 6; gsz = 2; }
  int j = (b >> 3) * gsz + gi;        // rank within group
  int wave = threadIdx.x >> 6;
  int segl = j * 4 + wave;            // local segment within metapath grp
  if (segl >= NN) return;
  int seg = grp * NN + segl;
  int m = grp;
  int lane = threadIdx.x & 63;

  int cnt = cursor[seg];
  cnt = cnt < CAP ? cnt : CAP;
  const unsigned* rp = erec + (size_t)seg * CAP;
  int g = lane >> 3, l8 = lane & 7;
  int h2 = l8;
  int c0 = l8 * 16;
  float er2 = er[seg * NH + h2];
  const float* elm = el + (size_t)m * NN * NH;
  const _Float16* fhm = fth + (size_t)m * NN * NF;

  float mx = -1e30f, sm = 0.f;
  float acc[16] = {};
  for (int i = g; i < cnt; i += 8) {
    unsigned rec = rp[i];
    int s = rec >> 17;
    float w = ((rec & 131071u) + 0.5f) * (1.f / 131072.f);
    float x2 = (elm[s * NH + h2] + er2) * w;
    x2 = x2 > 0.f ? x2 : 0.2f * x2;
    float nmx = fmaxf(mx, x2);
    float f = __expf(mx - nmx);
    float e = __expf(x2 - nmx);
    mx = nmx;
    sm = sm * f + e;
    const _Float16* fp = fhm + (size_t)s * NF + c0;
    half8 q0 = *(const half8*)(fp);
    half8 q1 = *(const half8*)(fp + 8);
#pragma unroll
    for (int k = 0; k < 8; ++k) acc[k] = fmaf(e, (float)q0[k], acc[k] * f);
#pragma unroll
    for (int k = 0; k < 8; ++k) acc[8 + k] = fmaf(e, (float)q1[k], acc[8 + k] * f);
  }
#pragma unroll
  for (int d = 8; d <= 32; d <<= 1) {
    float omx = __shfl_xor(mx, d);
    float osm = __shfl_xor(sm, d);
    float nmx = fmaxf(mx, omx);
    float f1 = __expf(mx - nmx), f2 = __expf(omx - nmx);
    sm = sm * f1 + osm * f2;
#pragma unroll
    for (int k = 0; k < 16; ++k) {
      float o = __shfl_xor(acc[k], d);
      acc[k] = acc[k] * f1 + o * f2;
    }
    mx = nmx;
  }
  if (g == 0) {
    float inv = sm > 0.f ? 1.f / sm : 0.f;
    const float* bp = bias + m * NF + c0;
    half8 zo0, zo1;
#pragma unroll
    for (int k = 0; k < 8; ++k) {
      float q = fmaf(acc[k], inv, bp[k]);
      q = q > 0.f ? q : __expf(q) - 1.f;
      zo0[k] = (_Float16)q;
      float q2 = fmaf(acc[8 + k], inv, bp[8 + k]);
      q2 = q2 > 0.f ? q2 : __expf(q2) - 1.f;
      zo1[k] = (_Float16)q2;
    }
    *(half8*)(zh + (size_t)seg * NF + c0) = zo0;
    *(half8*)(zh + (size_t)seg * NF + c0 + 8) = zo1;
  }
}

// ---- semantic: wsum[m] = sum_n w2 . tanh(zh[n,m,:] @ W1 + b1), MFMA ----
__global__ __launch_bounds__(256) void k_semgemm_mfma(
    const _Float16* __restrict__ zh, const _Float16* __restrict__ W1T,
    const float* __restrict__ b1, const float* __restrict__ w2,
    float* __restrict__ wsum) {
  __shared__ float msum[NM];
  int tid = threadIdx.x;
  if (tid < NM) msum[tid] = 0.f;
  __syncthreads();
  int wave = tid >> 6, lane = tid & 63;
  int l15 = lane & 15, kslot = lane >> 4;
  int rowbase = blockIdx.x * 64 + wave * 16;
  int arow = rowbase + l15;
  bool aok = arow < NSEG;
  const _Float16* Ap = zh + (size_t)(aok ? arow : 0) * NF + kslot * 8;
  const _Float16* Bp = W1T + (size_t)l15 * HID + kslot * 8;
  f32x4 acc[8];
#pragma unroll
  for (int c = 0; c < 8; ++c) acc[c] = (f32x4){0.f, 0.f, 0.f, 0.f};
#pragma unroll
  for (int kk = 0; kk < 4; ++kk) {
    int k0 = kk * 32;
    half8 a = {};
    if (aok) a = *(const half8*)(Ap + k0);
#pragma unroll
    for (int c = 0; c < 8; ++c) {
      half8 b = *(const half8*)(Bp + (size_t)c * 16 * HID + k0);
      acc[c] = __builtin_amdgcn_mfma_f32_16x16x32_f16(a, b, acc[c], 0, 0, 0);
    }
  }
  float p[4] = {0.f, 0.f, 0.f, 0.f};
#pragma unroll
  for (int c = 0; c < 8; ++c) {
    int col = c * 16 + l15;
    float b1r = b1[col];
    float w2r = w2[col];
#pragma unroll
    for (int j = 0; j < 4; ++j) p[j] += w2r * tanhf(acc[c][j] + b1r);
  }
#pragma unroll
  for (int j = 0; j < 4; ++j) {
#pragma unroll
    for (int off = 1; off < 16; off <<= 1) p[j] += __shfl_xor(p[j], off);
  }
  if (l15 == 0) {
#pragma unroll
    for (int j = 0; j < 4; ++j) {
      int r = rowbase + kslot * 4 + j;
      if (r < NSEG) atomicAdd(&msum[r / NN], p[j]);
    }
  }
  __syncthreads();
  if (tid < NM) {
    float v = msum[tid];
    if (v != 0.f) atomAddF(wsum + tid, v);
  }
}

// ---- output combine (vectorized, beta inline) ----
__global__ void k_out8(const _Float16* __restrict__ zh, const float* __restrict__ wsum,
                       float* __restrict__ out) {
  int t = blockIdx.x * 256 + threadIdx.x;
  if (t >= NN * NF / 8) return;
  float w0 = wsum[0] * (1.f / NN);
  float w1 = wsum[1] * (1.f / NN);
  float w2v = wsum[2] * (1.f / NN);
  float mxw = fmaxf(w0, fmaxf(w1, w2v));
  float e0 = __expf(w0 - mxw), e1 = __expf(w1 - mxw), e2 = __expf(w2v - mxw);
  float inv = 1.f / (e0 + e1 + e2);
  e0 *= inv; e1 *= inv; e2 *= inv;
  size_t base = (size_t)t * 8;
  half8 z0 = *(const half8*)(zh + base);
  half8 z1 = *(const half8*)(zh + (size_t)NN * NF + base);
  half8 z2 = *(const half8*)(zh + (size_t)2 * NN * NF + base);
  float o[8];
#pragma unroll
  for (int k = 0; k < 8; ++k)
    o[k] = e0 * (float)z0[k] + e1 * (float)z1[k] + e2 * (float)z2[k];
  *(float4*)(out + base) = make_float4(o[0], o[1], o[2], o[3]);
  *(float4*)(out + base + 4) = make_float4(o[4], o[5], o[6], o[7]);
}

extern "C" void kernel_launch(void* const* d_in, const int* in_sizes, int n_in,
                              void* d_out, int out_size, void* d_ws, size_t ws_size,
                              hipStream_t stream) {
  (void)in_sizes; (void)n_in; (void)out_size; (void)ws_size;
  const float* h    = (const float*)d_in[0];
  const float* fcW  = (const float*)d_in[1];
  const float* al   = (const float*)d_in[2];
  const float* ar   = (const float*)d_in[3];
  const float* bias = (const float*)d_in[4];
  const float* ew   = (const float*)d_in[5];
  const float* W1   = (const float*)d_in[6];
  const float* b1   = (const float*)d_in[7];
  const float* w2   = (const float*)d_in[8];
  const int* src    = (const int*)d_in[9];
  const int* dst    = (const int*)d_in[10];
  float* out = (float*)d_out;

  char* base = (char*)d_ws;
  size_t o = 0;
  int* cursor = (int*)(base + o); o += (size_t)NSEG * 4;
  float* wsum = (float*)(base + o); o += 8 * 4;
  o = (o + 15) & ~(size_t)15;
  unsigned* erec = (unsigned*)(base + o); o += (size_t)NSEG * CAP * 4;  // 30.7 MB
  float* el   = (float*)(base + o); o += (size_t)NSEG * NH * 4;
  float* er   = (float*)(base + o); o += (size_t)NSEG * NH * 4;
  _Float16* fth = (_Float16*)(base + o); o += (size_t)NM * NN * NF * 2;
  _Float16* h16 = (_Float16*)(base + o); o += (size_t)NN * NIN * 2;
  _Float16* WT  = (_Float16*)(base + o); o += (size_t)NM * NIN * NF * 2;
  _Float16* W1T = (_Float16*)(base + o); o += (size_t)NF * HID * 2;
  _Float16* zh  = (_Float16*)(base + o); o += (size_t)NM * NN * NF * 2;
  // total ~76 MB

  hipLaunchKernelGGL(k_prep, dim3(5000), dim3(256), 0, stream,
                     h, fcW, W1, h16, WT, W1T, cursor, wsum);
  hipLaunchKernelGGL(k_fill_gemm, dim3(3756), dim3(256), 0, stream,
                     src, dst, ew, cursor, erec, h16, WT, al, ar, fth, el, er);
  // grid 20008: covers rank j<5000 for the 2-XCD group (x in {6,7}); excess blocks return
  hipLaunchKernelGGL(k_aggr8, dim3(20008), dim3(256), 0, stream,
                     cursor, erec, el, er, fth, bias, zh);
  hipLaunchKernelGGL(k_semgemm_mfma, dim3(938), dim3(256), 0, stream,
                     zh, W1T, b1, w2, wsum);
  hipLaunchKernelGGL(k_out8, dim3(1250), dim3(256), 0, stream, zh, wsum, out);
}

// Round 16
// 211.295 us; speedup vs baseline: 1.2989x; 1.0913x over previous
//
#include <hip/hip_runtime.h>
#include <math.h>

#define NN 20000
#define NE 640000
#define NIN 256
#define NH 8
#define HD 16
#define NM 3
#define NF 128   // H*D
#define HID 128
#define NSEG (NM * NN)
#define CAP 128                      // slots per segment (max degree ~59, 12 sigma margin)

typedef __attribute__((ext_vector_type(4))) _Float16 half4;
typedef __attribute__((ext_vector_type(8))) _Float16 half8;
typedef __attribute__((ext_vector_type(4))) float f32x4;

__device__ __forceinline__ void atomAddF(float* p, float v) {
  unsafeAtomicAdd(p, v);
}

// ---- prep: fp16 conversions + zero cursor/wsum (pure streaming, no atomics) ----
__global__ void k_prep(const float* __restrict__ h, const float* __restrict__ fcW,
                       const float* __restrict__ W1, _Float16* __restrict__ h16,
                       _Float16* __restrict__ WT, _Float16* __restrict__ W1T,
                       int* __restrict__ cursor, float* __restrict__ wsum) {
  int t = blockIdx.x * 256 + threadIdx.x;
  if (t < NN * NIN / 4) {
    float4 v = *(const float4*)(h + 4 * t);
    half4 o = {(_Float16)v.x, (_Float16)v.y, (_Float16)v.z, (_Float16)v.w};
    *(half4*)(h16 + 4 * t) = o;
  }
  if (t < NM * NIN * NF) {              // WT[(m*128+n)*256+k] = fcW[m][k][n]
    int mm = t >> 15;
    int n = (t >> 8) & 127;
    int k = t & 255;
    WT[t] = (_Float16)fcW[(mm << 15) + (k << 7) + n];
  }
  if (t < NF * HID) {                   // W1T[n*128+k] = W1[k][n]
    int n = t >> 7;
    int k = t & 127;
    W1T[t] = (_Float16)W1[k * HID + n];
  }
  if (t < NSEG) cursor[t] = 0;
  if (t < 8) wsum[t] = 0.0f;
}

// ================= fused fill || gemm_elr =================
// 4-byte packed record: (src << 17) | ew_q17;  ew = (q+0.5)/2^17
// single-pass fixed-capacity binning: erec[seg*CAP + pos]; 4 edges/thread
__device__ __forceinline__ void fill_body(int fb, const int* __restrict__ src,
                                          const int* __restrict__ dst,
                                          const float* __restrict__ ew,
                                          int* __restrict__ cursor,
                                          unsigned* __restrict__ erec) {
  int e4 = (fb * 256 + threadIdx.x) * 4;
  if (e4 >= NM * NE) return;
  int4 d4 = *(const int4*)(dst + e4);
  int4 s4 = *(const int4*)(src + e4);
  float4 w4 = *(const float4*)(ew + e4);
  const int dd[4] = {d4.x, d4.y, d4.z, d4.w};
  const int ss[4] = {s4.x, s4.y, s4.z, s4.w};
  const float ww[4] = {w4.x, w4.y, w4.z, w4.w};
  int seg[4], pos[4];
#pragma unroll
  for (int j = 0; j < 4; ++j) {
    int m = (e4 + j) / NE;
    seg[j] = m * NN + dd[j];
    pos[j] = atomicAdd(cursor + seg[j], 1);
  }
#pragma unroll
  for (int j = 0; j < 4; ++j) {
    unsigned wq = (unsigned)fminf(ww[j] * 131072.f, 131071.f);
    if (pos[j] < CAP)
      __builtin_nontemporal_store(((unsigned)ss[j] << 17) | wq,
                                  erec + (size_t)seg[j] * CAP + pos[j]);
  }
}

__device__ __forceinline__ void gemm_body(int g, const _Float16* __restrict__ h16,
                                          const _Float16* __restrict__ WT,
                                          const float* __restrict__ al,
                                          const float* __restrict__ ar,
                                          _Float16* __restrict__ fth,
                                          float* __restrict__ el,
                                          float* __restrict__ er) {
  int bx = g % 313, by = g / 313;
  int tid = threadIdx.x;
  int wave = tid >> 6, lane = tid & 63;
  int l15 = lane & 15, kslot = lane >> 4;
  int m = by >> 1;
  int cin = (by & 1) << 6;
  int rowbase = bx * 64 + wave * 16;
  int arow = rowbase + l15;
  bool aok = arow < NN;
  const _Float16* Ap = h16 + (size_t)(aok ? arow : 0) * NIN + kslot * 8;
  const _Float16* Bp = WT + ((size_t)m * NF + cin + l15) * NIN + kslot * 8;
  f32x4 acc[4];
#pragma unroll
  for (int c = 0; c < 4; ++c) acc[c] = (f32x4){0.f, 0.f, 0.f, 0.f};
#pragma unroll
  for (int kk = 0; kk < 8; ++kk) {
    int k0 = kk * 32;
    half8 a = {};
    if (aok) a = *(const half8*)(Ap + k0);
#pragma unroll
    for (int c = 0; c < 4; ++c) {
      half8 b = *(const half8*)(Bp + (size_t)c * 16 * NIN + k0);
      acc[c] = __builtin_amdgcn_mfma_f32_16x16x32_f16(a, b, acc[c], 0, 0, 0);
    }
  }
  int orow0 = rowbase + kslot * 4;
#pragma unroll
  for (int j = 0; j < 4; ++j) {
    int r = orow0 + j;
    if (r < NN) {
      _Float16* op = fth + ((size_t)m * NN + r) * NF + cin + l15;
#pragma unroll
      for (int c = 0; c < 4; ++c) op[c * 16] = (_Float16)acc[c][j];
    }
  }
  float alr[4], arr_[4];
#pragma unroll
  for (int c = 0; c < 4; ++c) {
    int head = (cin >> 4) + c;
    alr[c] = al[(m * NH + head) * HD + l15];
    arr_[c] = ar[(m * NH + head) * HD + l15];
  }
#pragma unroll
  for (int c = 0; c < 4; ++c) {
    int head = (cin >> 4) + c;
#pragma unroll
    for (int j = 0; j < 4; ++j) {
      float v = acc[c][j] * alr[c];
      float u = acc[c][j] * arr_[c];
#pragma unroll
      for (int off = 1; off < 16; off <<= 1) {
        v += __shfl_xor(v, off);
        u += __shfl_xor(u, off);
      }
      int r = orow0 + j;
      if (l15 == 0 && r < NN) {
        size_t idx = ((size_t)m * NN + r) * NH + head;
        el[idx] = v;
        er[idx] = u;
      }
    }
  }
}

// grid 3756: even idx -> fill (1875 active), odd idx -> gemm (1878 active)  [round-11 optimum]
__global__ __launch_bounds__(256) void k_fill_gemm(
    const int* __restrict__ src, const int* __restrict__ dst,
    const float* __restrict__ ew, int* __restrict__ cursor,
    unsigned* __restrict__ erec, const _Float16* __restrict__ h16,
    const _Float16* __restrict__ WT, const float* __restrict__ al,
    const float* __restrict__ ar, _Float16* __restrict__ fth,
    float* __restrict__ el, float* __restrict__ er) {
  int idx = blockIdx.x;
  int half_ = idx >> 1;
  if (idx & 1) {
    if (half_ < 1878) gemm_body(half_, h16, WT, al, ar, fth, el, er);
  } else {
    if (half_ < 1875) fill_body(half_, src, dst, ew, cursor, erec);
  }
}

// ---- fused per-dst ONLINE softmax + aggregation, balanced XCD-slice mapping ----
// block b -> XCD b&7 (dispatch heuristic), rank r=b>>3 in [0,1875).
// segment = (xcd*1875 + r)*4 + wave: each XCD covers a contiguous 7500-segment
// slice; 6/8 XCDs see a single metapath's 5.1 MB gather working set.
// per wave: 8 edges/iter (8 lanes/edge, 16 cols/lane)
__global__ __launch_bounds__(256) void k_aggr8(
    const int* __restrict__ cursor, const unsigned* __restrict__ erec,
    const float* __restrict__ el, const float* __restrict__ er,
    const _Float16* __restrict__ fth, const float* __restrict__ bias,
    _Float16* __restrict__ zh) {
  int b = blockIdx.x;
  int xcd = b & 7;
  int r = b >> 3;                     // 0..1874
  int wave = threadIdx.x >> 6;
  int seg = (xcd * 1875 + r) * 4 + wave;   // 0..59999, balanced per XCD
  int lane = threadIdx.x & 63;
  int m = seg / NN;

  int cnt = cursor[seg];
  cnt = cnt < CAP ? cnt : CAP;
  const unsigned* rp = erec + (size_t)seg * CAP;
  int g = lane >> 3, l8 = lane & 7;
  int h2 = l8;
  int c0 = l8 * 16;
  float er2 = er[seg * NH + h2];
  const float* elm = el + (size_t)m * NN * NH;
  const _Float16* fhm = fth + (size_t)m * NN * NF;

  float mx = -1e30f, sm = 0.f;
  float acc[16] = {};
  for (int i = g; i < cnt; i += 8) {
    unsigned rec = rp[i];
    int s = rec >> 17;
    float w = ((rec & 131071u) + 0.5f) * (1.f / 131072.f);
    float x2 = (elm[s * NH + h2] + er2) * w;
    x2 = x2 > 0.f ? x2 : 0.2f * x2;
    float nmx = fmaxf(mx, x2);
    float f = __expf(mx - nmx);
    float e = __expf(x2 - nmx);
    mx = nmx;
    sm = sm * f + e;
    const _Float16* fp = fhm + (size_t)s * NF + c0;
    half8 q0 = *(const half8*)(fp);
    half8 q1 = *(const half8*)(fp + 8);
#pragma unroll
    for (int k = 0; k < 8; ++k) acc[k] = fmaf(e, (float)q0[k], acc[k] * f);
#pragma unroll
    for (int k = 0; k < 8; ++k) acc[8 + k] = fmaf(e, (float)q1[k], acc[8 + k] * f);
  }
#pragma unroll
  for (int d = 8; d <= 32; d <<= 1) {
    float omx = __shfl_xor(mx, d);
    float osm = __shfl_xor(sm, d);
    float nmx = fmaxf(mx, omx);
    float f1 = __expf(mx - nmx), f2 = __expf(omx - nmx);
    sm = sm * f1 + osm * f2;
#pragma unroll
    for (int k = 0; k < 16; ++k) {
      float o = __shfl_xor(acc[k], d);
      acc[k] = acc[k] * f1 + o * f2;
    }
    mx = nmx;
  }
  if (g == 0) {
    float inv = sm > 0.f ? 1.f / sm : 0.f;
    const float* bp = bias + m * NF + c0;
    half8 zo0, zo1;
#pragma unroll
    for (int k = 0; k < 8; ++k) {
      float q = fmaf(acc[k], inv, bp[k]);
      q = q > 0.f ? q : __expf(q) - 1.f;
      zo0[k] = (_Float16)q;
      float q2 = fmaf(acc[8 + k], inv, bp[8 + k]);
      q2 = q2 > 0.f ? q2 : __expf(q2) - 1.f;
      zo1[k] = (_Float16)q2;
    }
    *(half8*)(zh + (size_t)seg * NF + c0) = zo0;
    *(half8*)(zh + (size_t)seg * NF + c0 + 8) = zo1;
  }
}

// ---- semantic: wsum[m] = sum_n w2 . tanh(zh[n,m,:] @ W1 + b1), MFMA ----
__global__ __launch_bounds__(256) void k_semgemm_mfma(
    const _Float16* __restrict__ zh, const _Float16* __restrict__ W1T,
    const float* __restrict__ b1, const float* __restrict__ w2,
    float* __restrict__ wsum) {
  __shared__ float msum[NM];
  int tid = threadIdx.x;
  if (tid < NM) msum[tid] = 0.f;
  __syncthreads();
  int wave = tid >> 6, lane = tid & 63;
  int l15 = lane & 15, kslot = lane >> 4;
  int rowbase = blockIdx.x * 64 + wave * 16;
  int arow = rowbase + l15;
  bool aok = arow < NSEG;
  const _Float16* Ap = zh + (size_t)(aok ? arow : 0) * NF + kslot * 8;
  const _Float16* Bp = W1T + (size_t)l15 * HID + kslot * 8;
  f32x4 acc[8];
#pragma unroll
  for (int c = 0; c < 8; ++c) acc[c] = (f32x4){0.f, 0.f, 0.f, 0.f};
#pragma unroll
  for (int kk = 0; kk < 4; ++kk) {
    int k0 = kk * 32;
    half8 a = {};
    if (aok) a = *(const half8*)(Ap + k0);
#pragma unroll
    for (int c = 0; c < 8; ++c) {
      half8 b = *(const half8*)(Bp + (size_t)c * 16 * HID + k0);
      acc[c] = __builtin_amdgcn_mfma_f32_16x16x32_f16(a, b, acc[c], 0, 0, 0);
    }
  }
  float p[4] = {0.f, 0.f, 0.f, 0.f};
#pragma unroll
  for (int c = 0; c < 8; ++c) {
    int col = c * 16 + l15;
    float b1r = b1[col];
    float w2r = w2[col];
#pragma unroll
    for (int j = 0; j < 4; ++j) p[j] += w2r * tanhf(acc[c][j] + b1r);
  }
#pragma unroll
  for (int j = 0; j < 4; ++j) {
#pragma unroll
    for (int off = 1; off < 16; off <<= 1) p[j] += __shfl_xor(p[j], off);
  }
  if (l15 == 0) {
#pragma unroll
    for (int j = 0; j < 4; ++j) {
      int r = rowbase + kslot * 4 + j;
      if (r < NSEG) atomicAdd(&msum[r / NN], p[j]);
    }
  }
  __syncthreads();
  if (tid < NM) {
    float v = msum[tid];
    if (v != 0.f) atomAddF(wsum + tid, v);
  }
}

// ---- output combine (vectorized, beta inline) ----
__global__ void k_out8(const _Float16* __restrict__ zh, const float* __restrict__ wsum,
                       float* __restrict__ out) {
  int t = blockIdx.x * 256 + threadIdx.x;
  if (t >= NN * NF / 8) return;
  float w0 = wsum[0] * (1.f / NN);
  float w1 = wsum[1] * (1.f / NN);
  float w2v = wsum[2] * (1.f / NN);
  float mxw = fmaxf(w0, fmaxf(w1, w2v));
  float e0 = __expf(w0 - mxw), e1 = __expf(w1 - mxw), e2 = __expf(w2v - mxw);
  float inv = 1.f / (e0 + e1 + e2);
  e0 *= inv; e1 *= inv; e2 *= inv;
  size_t base = (size_t)t * 8;
  half8 z0 = *(const half8*)(zh + base);
  half8 z1 = *(const half8*)(zh + (size_t)NN * NF + base);
  half8 z2 = *(const half8*)(zh + (size_t)2 * NN * NF + base);
  float o[8];
#pragma unroll
  for (int k = 0; k < 8; ++k)
    o[k] = e0 * (float)z0[k] + e1 * (float)z1[k] + e2 * (float)z2[k];
  *(float4*)(out + base) = make_float4(o[0], o[1], o[2], o[3]);
  *(float4*)(out + base + 4) = make_float4(o[4], o[5], o[6], o[7]);
}

extern "C" void kernel_launch(void* const* d_in, const int* in_sizes, int n_in,
                              void* d_out, int out_size, void* d_ws, size_t ws_size,
                              hipStream_t stream) {
  (void)in_sizes; (void)n_in; (void)out_size; (void)ws_size;
  const float* h    = (const float*)d_in[0];
  const float* fcW  = (const float*)d_in[1];
  const float* al   = (const float*)d_in[2];
  const float* ar   = (const float*)d_in[3];
  const float* bias = (const float*)d_in[4];
  const float* ew   = (const float*)d_in[5];
  const float* W1   = (const float*)d_in[6];
  const float* b1   = (const float*)d_in[7];
  const float* w2   = (const float*)d_in[8];
  const int* src    = (const int*)d_in[9];
  const int* dst    = (const int*)d_in[10];
  float* out = (float*)d_out;

  char* base = (char*)d_ws;
  size_t o = 0;
  int* cursor = (int*)(base + o); o += (size_t)NSEG * 4;
  float* wsum = (float*)(base + o); o += 8 * 4;
  o = (o + 15) & ~(size_t)15;
  unsigned* erec = (unsigned*)(base + o); o += (size_t)NSEG * CAP * 4;  // 30.7 MB
  float* el   = (float*)(base + o); o += (size_t)NSEG * NH * 4;
  float* er   = (float*)(base + o); o += (size_t)NSEG * NH * 4;
  _Float16* fth = (_Float16*)(base + o); o += (size_t)NM * NN * NF * 2;
  _Float16* h16 = (_Float16*)(base + o); o += (size_t)NN * NIN * 2;
  _Float16* WT  = (_Float16*)(base + o); o += (size_t)NM * NIN * NF * 2;
  _Float16* W1T = (_Float16*)(base + o); o += (size_t)NF * HID * 2;
  _Float16* zh  = (_Float16*)(base + o); o += (size_t)NM * NN * NF * 2;
  // total ~76 MB

  hipLaunchKernelGGL(k_prep, dim3(5000), dim3(256), 0, stream,
                     h, fcW, W1, h16, WT, W1T, cursor, wsum);
  hipLaunchKernelGGL(k_fill_gemm, dim3(3756), dim3(256), 0, stream,
                     src, dst, ew, cursor, erec, h16, WT, al, ar, fth, el, er);
  hipLaunchKernelGGL(k_aggr8, dim3(15000), dim3(256), 0, stream,
                     cursor, erec, el, er, fth, bias, zh);
  hipLaunchKernelGGL(k_semgemm_mfma, dim3(938), dim3(256), 0, stream,
                     zh, W1T, b1, w2, wsum);
  hipLaunchKernelGGL(k_out8, dim3(1250), dim3(256), 0, stream, zh, wsum, out);
}